// Round 1
// baseline (1780.078 us; speedup 1.0000x reference)
//
#include <hip/hip_runtime.h>

#define N_PTS 4096
#define B_SZ  8
#define M_OUT 1024
#define NS    64
#define CIN   128
#define COUT  256

// ---------------------------------------------------------------------------
// 1) Furthest point sampling — one block per batch, sequential over 1024 steps.
//    Points + running min-dist live in registers (16 pts/thread @ 256 threads).
//    Argmax carries (val, idx, x, y, z) through a 64-lane xor butterfly, then a
//    4-entry LDS combine. Tie-break: lower index wins (matches jnp.argmax).
// ---------------------------------------------------------------------------
__global__ __launch_bounds__(256) void fps_kernel(const float* __restrict__ xyz,
                                                  int* __restrict__ fps_idx) {
#pragma clang fp contract(off)
  const int b = blockIdx.x;
  const int t = threadIdx.x;
  const float* base = xyz + b * N_PTS * 3;
  float px[16], py[16], pz[16], mind[16];
#pragma unroll
  for (int j = 0; j < 16; ++j) {
    int n = j * 256 + t;
    px[j] = base[n * 3 + 0];
    py[j] = base[n * 3 + 1];
    pz[j] = base[n * 3 + 2];
    mind[j] = 1e10f;
  }
  __shared__ float sv[4], sx[4], sy[4], sz[4];
  __shared__ int si[4];
  int cur = 0;
  float cx = base[0], cy = base[1], cz = base[2];
  const int lane = t & 63, wv = t >> 6;
  int* out = fps_idx + b * M_OUT;
  for (int i = 0; i < M_OUT; ++i) {
    if (t == 0) out[i] = cur;
    float bv = -1.0f, bx = 0.f, by = 0.f, bz = 0.f;
    int bi = 0;
#pragma unroll
    for (int j = 0; j < 16; ++j) {
      float dx = px[j] - cx, dy = py[j] - cy, dz = pz[j] - cz;
      float d = dx * dx + dy * dy;   // contract(off): match numpy op order
      d = d + dz * dz;
      float md = fminf(mind[j], d);
      mind[j] = md;
      // ascending j => ascending global index; strict > keeps first max
      if (md > bv) { bv = md; bi = j * 256 + t; bx = px[j]; by = py[j]; bz = pz[j]; }
    }
#pragma unroll
    for (int off = 32; off > 0; off >>= 1) {
      float ov = __shfl_xor(bv, off);
      int   oi = __shfl_xor(bi, off);
      float ox = __shfl_xor(bx, off);
      float oy = __shfl_xor(by, off);
      float oz = __shfl_xor(bz, off);
      if (ov > bv || (ov == bv && oi < bi)) { bv = ov; bi = oi; bx = ox; by = oy; bz = oz; }
    }
    if (lane == 0) { sv[wv] = bv; si[wv] = bi; sx[wv] = bx; sy[wv] = by; sz[wv] = bz; }
    __syncthreads();
    bv = sv[0]; bi = si[0]; bx = sx[0]; by = sy[0]; bz = sz[0];
#pragma unroll
    for (int w = 1; w < 4; ++w) {
      float ov = sv[w]; int oi = si[w];
      if (ov > bv || (ov == bv && oi < bi)) { bv = ov; bi = oi; bx = sx[w]; by = sy[w]; bz = sz[w]; }
    }
    cur = bi; cx = bx; cy = by; cz = bz;
    __syncthreads();
  }
}

// ---------------------------------------------------------------------------
// 2) Ball query — one wave per (b, m). Ordered compaction over n via ballot +
//    prefix popcount; first NS in-ball indices in ascending order, padded with
//    the first hit. Strict d2 < r^2 in un-contracted f32 (matches reference).
// ---------------------------------------------------------------------------
__global__ __launch_bounds__(256) void ballq_kernel(const float* __restrict__ xyz,
                                                    const int* __restrict__ fps_idx,
                                                    int* __restrict__ idx_out) {
#pragma clang fp contract(off)
  const int p = blockIdx.x * 4 + (threadIdx.x >> 6);
  const int lane = threadIdx.x & 63;
  const int b = p >> 10;
  const float* base = xyz + b * N_PTS * 3;
  const int cidx = fps_idx[p];
  const float cx = base[cidx * 3 + 0], cy = base[cidx * 3 + 1], cz = base[cidx * 3 + 2];
  int* out = idx_out + p * NS;
  int cnt = 0, first = 0;
  for (int c = 0; c < N_PTS / 64 && cnt < NS; ++c) {
    const int n = c * 64 + lane;
    float dx = base[n * 3 + 0] - cx;
    float dy = base[n * 3 + 1] - cy;
    float dz = base[n * 3 + 2] - cz;
    float d = dx * dx + dy * dy;
    d = d + dz * dz;
    const bool inb = d < 0.1024f;  // f32(RADIUS^2), matches JAX weak-scalar promotion
    unsigned long long mask = __ballot(inb);
    if (cnt == 0 && mask) first = c * 64 + (__ffsll(mask) - 1);
    const int pos = cnt + __popcll(mask & ((1ull << lane) - 1ull));
    if (inb && pos < NS) out[pos] = n;
    cnt += (int)__popcll(mask);
  }
  if (lane >= cnt) out[lane] = first;  // pad (center itself guarantees cnt >= 1)
}

// ---------------------------------------------------------------------------
// 3) Pointwise conv on ALL 4096 points (conv commutes with gather): per batch
//    Z[n,o] = sum_c F[c,n] * W[o,c].  Tiled 64n x 64o, BK=32, 4x4 microtile.
//    Z stored [B][N][O] so the pool gather is coalesced across o-lanes.
// ---------------------------------------------------------------------------
__global__ __launch_bounds__(256) void conv_kernel(const float* __restrict__ F,
                                                   const float* __restrict__ W,
                                                   float* __restrict__ Z) {
  __shared__ float Bs[CIN][64 + 4];  // [c][o]
  __shared__ float As[32][64 + 4];   // [c][n]
  const int b = blockIdx.z;
  const int n0 = blockIdx.x * 64, o0 = blockIdx.y * 64;
  const int tid = threadIdx.x;
  // Load full W o-tile (64 x 128) once; coalesced in c.
  for (int l = 0; l < 32; ++l) {
    int e = l * 256 + tid;
    int c = e & 127, oo = e >> 7;
    Bs[c][oo] = W[(o0 + oo) * CIN + c];
  }
  float acc[4][4] = {};
  const int tx = tid & 15, ty = tid >> 4;  // tx -> n micro, ty -> o micro
  const float* Fb = F + b * CIN * N_PTS;
  for (int c0 = 0; c0 < CIN; c0 += 32) {
    __syncthreads();
    for (int l = 0; l < 8; ++l) {
      int e = l * 256 + tid;
      int nn = e & 63, cc = e >> 6;
      As[cc][nn] = Fb[(c0 + cc) * N_PTS + n0 + nn];
    }
    __syncthreads();
#pragma unroll
    for (int cc = 0; cc < 32; ++cc) {
      float4 a = *(const float4*)&As[cc][tx * 4];
      float4 w4 = *(const float4*)&Bs[c0 + cc][ty * 4];
      acc[0][0] += a.x * w4.x; acc[0][1] += a.x * w4.y; acc[0][2] += a.x * w4.z; acc[0][3] += a.x * w4.w;
      acc[1][0] += a.y * w4.x; acc[1][1] += a.y * w4.y; acc[1][2] += a.y * w4.z; acc[1][3] += a.y * w4.w;
      acc[2][0] += a.z * w4.x; acc[2][1] += a.z * w4.y; acc[2][2] += a.z * w4.z; acc[2][3] += a.z * w4.w;
      acc[3][0] += a.w * w4.x; acc[3][1] += a.w * w4.y; acc[3][2] += a.w * w4.z; acc[3][3] += a.w * w4.w;
    }
  }
  float* Zb = Z + (size_t)(b * N_PTS + n0) * COUT + o0;
#pragma unroll
  for (int i = 0; i < 4; ++i) {
    int nn = tx * 4 + i;
    float4 v = make_float4(acc[i][0], acc[i][1], acc[i][2], acc[i][3]);
    *(float4*)&Zb[(size_t)nn * COUT + ty * 4] = v;
  }
}

// ---------------------------------------------------------------------------
// 4) Gather + max-pool + BN + ReLU. max commutes with the (positive-scale)
//    monotone affine + relu, so pool raw conv outputs then apply epilogue once.
//    Block = (b, 16-m tile) x 256 threads (one per o). LDS transpose for
//    coalesced [B][O][M] writes.
// ---------------------------------------------------------------------------
__global__ __launch_bounds__(256) void pool_kernel(const float* __restrict__ Z,
                                                   const int* __restrict__ idx,
                                                   const float* __restrict__ bias,
                                                   const float* __restrict__ gamma,
                                                   const float* __restrict__ beta,
                                                   const float* __restrict__ rmean,
                                                   const float* __restrict__ rvar,
                                                   float* __restrict__ out) {
  __shared__ float T[COUT][17];
  const int b = blockIdx.x >> 6;           // 64 m-tiles of 16 per batch
  const int m0 = (blockIdx.x & 63) * 16;
  const int o = threadIdx.x;
  const float sc = gamma[o] * (1.0f / sqrtf(rvar[o] + 1e-5f));
  const float bo = bias[o], mo = rmean[o], bt = beta[o];
  const float* Zb = Z + (size_t)b * N_PTS * COUT;
  const int* ib = idx + (size_t)(b * M_OUT + m0) * NS;
  for (int mi = 0; mi < 16; ++mi) {
    float best = -1e30f;
#pragma unroll 4
    for (int s = 0; s < NS; ++s) {
      int n = ib[mi * NS + s];
      best = fmaxf(best, Zb[(size_t)n * COUT + o]);
    }
    float t = best + bo;
    t = (t - mo) * sc + bt;
    T[o][mi] = fmaxf(t, 0.0f);
  }
  __syncthreads();
  for (int l = 0; l < 16; ++l) {
    int e = l * 256 + (int)threadIdx.x;
    int mm = e & 15, oo = e >> 4;
    out[(size_t)(b * COUT + oo) * M_OUT + m0 + mm] = T[oo][mm];
  }
}

extern "C" void kernel_launch(void* const* d_in, const int* in_sizes, int n_in,
                              void* d_out, int out_size, void* d_ws, size_t ws_size,
                              hipStream_t stream) {
  const float* xyz      = (const float*)d_in[0];
  const float* features = (const float*)d_in[1];
  const float* W        = (const float*)d_in[2];
  const float* bias     = (const float*)d_in[3];
  const float* gamma    = (const float*)d_in[4];
  const float* beta     = (const float*)d_in[5];
  const float* rmean    = (const float*)d_in[6];
  const float* rvar     = (const float*)d_in[7];
  float* out = (float*)d_out;

  char* ws = (char*)d_ws;
  int* fps  = (int*)ws;                                  // 32 KB
  int* bidx = (int*)(ws + (64 << 10));                   // 2 MB
  float* Z  = (float*)(ws + (64 << 10) + (2 << 20));     // 33.5 MB

  fps_kernel<<<B_SZ, 256, 0, stream>>>(xyz, fps);
  ballq_kernel<<<(B_SZ * M_OUT) / 4, 256, 0, stream>>>(xyz, fps, bidx);
  conv_kernel<<<dim3(N_PTS / 64, COUT / 64, B_SZ), 256, 0, stream>>>(features, W, Z);
  pool_kernel<<<B_SZ * (M_OUT / 16), 256, 0, stream>>>(Z, bidx, bias, gamma, beta, rmean, rvar, out);
}

// Round 2
// 1104.490 us; speedup vs baseline: 1.6117x; 1.6117x over previous
//
#include <hip/hip_runtime.h>

#define N_PTS 4096
#define B_SZ  8
#define M_OUT 1024
#define NS    64
#define CIN   128
#define COUT  256

typedef float v2f __attribute__((ext_vector_type(2)));

// Wave-64 max reduce via DPP (row_shr 1/2/4/8, bcast15, bcast31), result
// broadcast to all lanes through readlane(63). Values are >= -1 (squared
// dists); invalid DPP source lanes fall back to `old` = own value (identity).
__device__ __forceinline__ float dpp_max_f32(float v) {
  int x = __builtin_bit_cast(int, v);
#define STG(C)                                                              \
  {                                                                         \
    int y = __builtin_amdgcn_update_dpp(x, x, C, 0xF, 0xF, false);          \
    float a = __builtin_bit_cast(float, x);                                 \
    float b2 = __builtin_bit_cast(float, y);                                \
    a = fmaxf(a, b2);                                                       \
    x = __builtin_bit_cast(int, a);                                         \
  }
  STG(0x111) STG(0x112) STG(0x114) STG(0x118) STG(0x142) STG(0x143)
#undef STG
  return __builtin_bit_cast(float, __builtin_amdgcn_readlane(x, 63));
}

__device__ __forceinline__ unsigned dpp_min_u32(unsigned v) {
  int x = (int)v;
#define STG(C)                                                              \
  {                                                                         \
    int y = __builtin_amdgcn_update_dpp(x, x, C, 0xF, 0xF, false);          \
    unsigned a = (unsigned)x, bb = (unsigned)y;                             \
    x = (int)(a < bb ? a : bb);                                             \
  }
  STG(0x111) STG(0x112) STG(0x114) STG(0x118) STG(0x142) STG(0x143)
#undef STG
  return (unsigned)__builtin_amdgcn_readlane(x, 63);
}

// ---------------------------------------------------------------------------
// 1) Furthest point sampling — one block per batch. 16 pts/thread held as 8
//    packed float2 (v_pk_* math, identical rounding to scalar). Per step:
//    packed mind update + packed running max -> wave DPP f32-max -> exact-
//    equality rescan for per-thread min tied index -> wave DPP u32-min ->
//    per-wave (val,idx) to parity-double-buffered LDS slots -> ONE barrier ->
//    4-slot serial combine. Winner coords via broadcast LDS read of xyz copy.
//    Tie-break everywhere: lower index wins (matches jnp.argmax).
// ---------------------------------------------------------------------------
__global__ __launch_bounds__(256) void fps_kernel(const float* __restrict__ xyz,
                                                  int* __restrict__ fps_idx) {
#pragma clang fp contract(off)
  __shared__ float lx[N_PTS], ly[N_PTS], lz[N_PTS];
  __shared__ float svals[2][4];
  __shared__ unsigned sidxs[2][4];
  const int b = blockIdx.x, t = threadIdx.x;
  const int lane = t & 63, wv = t >> 6;
  const float* base = xyz + b * N_PTS * 3;
  for (int e = t; e < N_PTS; e += 256) {
    lx[e] = base[e * 3 + 0];
    ly[e] = base[e * 3 + 1];
    lz[e] = base[e * 3 + 2];
  }
  __syncthreads();
  v2f px[8], py[8], pz[8], m2[8];
#pragma unroll
  for (int j = 0; j < 8; ++j) {
    int n0 = (2 * j) * 256 + t, n1 = (2 * j + 1) * 256 + t;
    px[j] = (v2f){lx[n0], lx[n1]};
    py[j] = (v2f){ly[n0], ly[n1]};
    pz[j] = (v2f){lz[n0], lz[n1]};
    m2[j] = (v2f){1e10f, 1e10f};
  }
  int cur = 0;
  float cx = lx[0], cy = ly[0], cz = lz[0];
  int* out = fps_idx + b * M_OUT;
  for (int i = 0; i < M_OUT; ++i) {
    if (t == 0) out[i] = cur;
    v2f bv2 = (v2f){-1.0f, -1.0f};
#pragma unroll
    for (int j = 0; j < 8; ++j) {
      v2f dx = px[j] - cx, dy = py[j] - cy, dz = pz[j] - cz;
      v2f d = dx * dx + dy * dy;  // contract(off): numpy op order, no FMA
      d = d + dz * dz;
      v2f md = __builtin_elementwise_min(m2[j], d);
      m2[j] = md;
      bv2 = __builtin_elementwise_max(bv2, md);
    }
    float bv = fmaxf(bv2.x, bv2.y);
    const float mv = dpp_max_f32(bv);  // wave max, all lanes
    unsigned mi = 0xFFFFFFFFu;
#pragma unroll
    for (int j = 0; j < 8; ++j) {
      if (m2[j].x == mv) {
        unsigned c0 = (unsigned)((2 * j) * 256 + t);
        mi = mi < c0 ? mi : c0;
      }
      if (m2[j].y == mv) {
        unsigned c1 = (unsigned)((2 * j + 1) * 256 + t);
        mi = mi < c1 ? mi : c1;
      }
    }
    const unsigned miw = dpp_min_u32(mi);  // wave min tied index
    const int p = i & 1;
    if (lane == 0) {
      svals[p][wv] = mv;
      sidxs[p][wv] = miw;
    }
    __syncthreads();  // the only barrier per step (slots parity-buffered)
    float gv = svals[p][0];
    unsigned gi = sidxs[p][0];
#pragma unroll
    for (int w = 1; w < 4; ++w) {
      float v = svals[p][w];
      unsigned ii = sidxs[p][w];
      bool bt = (v > gv) || (v == gv && ii < gi);
      gv = bt ? v : gv;
      gi = bt ? ii : gi;
    }
    cur = (int)gi;
    cx = lx[gi];
    cy = ly[gi];
    cz = lz[gi];
  }
}

// ---------------------------------------------------------------------------
// 2) Ball query — one wave per (b, m). Ordered compaction over n via ballot +
//    prefix popcount; first NS in-ball indices in ascending order, padded with
//    the first hit. Strict d2 < r^2 in un-contracted f32 (matches reference).
// ---------------------------------------------------------------------------
__global__ __launch_bounds__(256) void ballq_kernel(const float* __restrict__ xyz,
                                                    const int* __restrict__ fps_idx,
                                                    int* __restrict__ idx_out) {
#pragma clang fp contract(off)
  const int p = blockIdx.x * 4 + (threadIdx.x >> 6);
  const int lane = threadIdx.x & 63;
  const int b = p >> 10;
  const float* base = xyz + b * N_PTS * 3;
  const int cidx = fps_idx[p];
  const float cx = base[cidx * 3 + 0], cy = base[cidx * 3 + 1], cz = base[cidx * 3 + 2];
  int* out = idx_out + p * NS;
  int cnt = 0, first = 0;
  for (int c = 0; c < N_PTS / 64 && cnt < NS; ++c) {
    const int n = c * 64 + lane;
    float dx = base[n * 3 + 0] - cx;
    float dy = base[n * 3 + 1] - cy;
    float dz = base[n * 3 + 2] - cz;
    float d = dx * dx + dy * dy;
    d = d + dz * dz;
    const bool inb = d < 0.1024f;  // f32(RADIUS^2), matches JAX weak-scalar promotion
    unsigned long long mask = __ballot(inb);
    if (cnt == 0 && mask) first = c * 64 + (__ffsll(mask) - 1);
    const int pos = cnt + __popcll(mask & ((1ull << lane) - 1ull));
    if (inb && pos < NS) out[pos] = n;
    cnt += (int)__popcll(mask);
  }
  if (lane >= cnt) out[lane] = first;  // pad (center itself guarantees cnt >= 1)
}

// ---------------------------------------------------------------------------
// 3) Pointwise conv on ALL 4096 points (conv commutes with gather): per batch
//    Z[n,o] = sum_c F[c,n] * W[o,c].  Tiled 64n x 64o, BK=32, 4x4 microtile.
//    Z stored [B][N][O] so the pool gather is coalesced across o-lanes.
// ---------------------------------------------------------------------------
__global__ __launch_bounds__(256) void conv_kernel(const float* __restrict__ F,
                                                   const float* __restrict__ W,
                                                   float* __restrict__ Z) {
  __shared__ float Bs[CIN][64 + 4];  // [c][o]
  __shared__ float As[32][64 + 4];   // [c][n]
  const int b = blockIdx.z;
  const int n0 = blockIdx.x * 64, o0 = blockIdx.y * 64;
  const int tid = threadIdx.x;
  for (int l = 0; l < 32; ++l) {
    int e = l * 256 + tid;
    int c = e & 127, oo = e >> 7;
    Bs[c][oo] = W[(o0 + oo) * CIN + c];
  }
  float acc[4][4] = {};
  const int tx = tid & 15, ty = tid >> 4;
  const float* Fb = F + b * CIN * N_PTS;
  for (int c0 = 0; c0 < CIN; c0 += 32) {
    __syncthreads();
    for (int l = 0; l < 8; ++l) {
      int e = l * 256 + tid;
      int nn = e & 63, cc = e >> 6;
      As[cc][nn] = Fb[(c0 + cc) * N_PTS + n0 + nn];
    }
    __syncthreads();
#pragma unroll
    for (int cc = 0; cc < 32; ++cc) {
      float4 a = *(const float4*)&As[cc][tx * 4];
      float4 w4 = *(const float4*)&Bs[c0 + cc][ty * 4];
      acc[0][0] += a.x * w4.x; acc[0][1] += a.x * w4.y; acc[0][2] += a.x * w4.z; acc[0][3] += a.x * w4.w;
      acc[1][0] += a.y * w4.x; acc[1][1] += a.y * w4.y; acc[1][2] += a.y * w4.z; acc[1][3] += a.y * w4.w;
      acc[2][0] += a.z * w4.x; acc[2][1] += a.z * w4.y; acc[2][2] += a.z * w4.z; acc[2][3] += a.z * w4.w;
      acc[3][0] += a.w * w4.x; acc[3][1] += a.w * w4.y; acc[3][2] += a.w * w4.z; acc[3][3] += a.w * w4.w;
    }
  }
  float* Zb = Z + (size_t)(b * N_PTS + n0) * COUT + o0;
#pragma unroll
  for (int i = 0; i < 4; ++i) {
    int nn = tx * 4 + i;
    float4 v = make_float4(acc[i][0], acc[i][1], acc[i][2], acc[i][3]);
    *(float4*)&Zb[(size_t)nn * COUT + ty * 4] = v;
  }
}

// ---------------------------------------------------------------------------
// 4) Gather + max-pool + BN + ReLU. max commutes with the (positive-scale)
//    monotone affine + relu, so pool raw conv outputs then apply epilogue once.
// ---------------------------------------------------------------------------
__global__ __launch_bounds__(256) void pool_kernel(const float* __restrict__ Z,
                                                   const int* __restrict__ idx,
                                                   const float* __restrict__ bias,
                                                   const float* __restrict__ gamma,
                                                   const float* __restrict__ beta,
                                                   const float* __restrict__ rmean,
                                                   const float* __restrict__ rvar,
                                                   float* __restrict__ out) {
  __shared__ float T[COUT][17];
  const int b = blockIdx.x >> 6;
  const int m0 = (blockIdx.x & 63) * 16;
  const int o = threadIdx.x;
  const float sc = gamma[o] * (1.0f / sqrtf(rvar[o] + 1e-5f));
  const float bo = bias[o], mo = rmean[o], bt = beta[o];
  const float* Zb = Z + (size_t)b * N_PTS * COUT;
  const int* ib = idx + (size_t)(b * M_OUT + m0) * NS;
  for (int mi = 0; mi < 16; ++mi) {
    float best = -1e30f;
#pragma unroll 4
    for (int s = 0; s < NS; ++s) {
      int n = ib[mi * NS + s];
      best = fmaxf(best, Zb[(size_t)n * COUT + o]);
    }
    float t = best + bo;
    t = (t - mo) * sc + bt;
    T[o][mi] = fmaxf(t, 0.0f);
  }
  __syncthreads();
  for (int l = 0; l < 16; ++l) {
    int e = l * 256 + (int)threadIdx.x;
    int mm = e & 15, oo = e >> 4;
    out[(size_t)(b * COUT + oo) * M_OUT + m0 + mm] = T[oo][mm];
  }
}

extern "C" void kernel_launch(void* const* d_in, const int* in_sizes, int n_in,
                              void* d_out, int out_size, void* d_ws, size_t ws_size,
                              hipStream_t stream) {
  const float* xyz      = (const float*)d_in[0];
  const float* features = (const float*)d_in[1];
  const float* W        = (const float*)d_in[2];
  const float* bias     = (const float*)d_in[3];
  const float* gamma    = (const float*)d_in[4];
  const float* beta     = (const float*)d_in[5];
  const float* rmean    = (const float*)d_in[6];
  const float* rvar     = (const float*)d_in[7];
  float* out = (float*)d_out;

  char* ws = (char*)d_ws;
  int* fps  = (int*)ws;                                  // 32 KB
  int* bidx = (int*)(ws + (64 << 10));                   // 2 MB
  float* Z  = (float*)(ws + (64 << 10) + (2 << 20));     // 33.5 MB

  fps_kernel<<<B_SZ, 256, 0, stream>>>(xyz, fps);
  ballq_kernel<<<(B_SZ * M_OUT) / 4, 256, 0, stream>>>(xyz, fps, bidx);
  conv_kernel<<<dim3(N_PTS / 64, COUT / 64, B_SZ), 256, 0, stream>>>(features, W, Z);
  pool_kernel<<<B_SZ * (M_OUT / 16), 256, 0, stream>>>(Z, bidx, bias, gamma, beta, rmean, rvar, out);
}